// Round 13
// baseline (101.616 us; speedup 1.0000x reference)
//
#include <hip/hip_runtime.h>
#include <math.h>

#define NPTS 8192
#define GD 8
#define NCELL 512                  // GD^3
#define CELL_H (0.3f/(float)GD)    // 0.0375 > 0.02 alignment radius
#define INV_H ((float)GD/0.3f)
#define ALIGN_T 4.0e-4f            // 0.02^2
#define K5 5
#define K9 9
#define CAP 768                    // LDS staging capacity (box ~430)
#define QBLK 1024                  // query blocks: 2 per cell

// ws layout (bytes) — gcnt/flat/cntr contiguous: ONE 2056-B memset clears all
#define WS_GCNT   0                // int[NCELL] (2048 B)
#define WS_FLAT   2048             // float: global flatness sum
#define WS_CNTR   2052             // uint: completion counter
#define WS_PART   2064             // float4[QBLK] partials (16 KB)
#define WS_SPOS   18448            // float4[NPTS] sorted (x,y,z,|p|^2)
#define WS_SROT   149520           // float4[NPTS] sorted rotations
#define WS_SOPA   280592           // float[NPTS] sorted opacity
#define WS_CSTART 313360           // int[NCELL+1]
#define WS_AUX    315416           // int[NPTS] packed (cell | slot<<9)

// ---------------- build 1: count + flatness ----------------
__global__ __launch_bounds__(256) void gsr_count(
    const float* __restrict__ pos, const float* __restrict__ scl,
    unsigned char* __restrict__ ws)
{
    int* gcnt = (int*)(ws + WS_GCNT);
    float* flatAcc = (float*)(ws + WS_FLAT);
    int* aux = (int*)(ws + WS_AUX);

    const int p = blockIdx.x*256 + threadIdx.x;
    const int lane = threadIdx.x & 63;

    float x = pos[3*p], y = pos[3*p+1], z = pos[3*p+2];
    int ix = min((int)(x*INV_H), GD-1);
    int iy = min((int)(y*INV_H), GD-1);
    int iz = min((int)(z*INV_H), GD-1);
    int c = (ix*GD+iy)*GD+iz;
    int slot = atomicAdd(&gcnt[c], 1);
    aux[p] = c | (slot << 9);

    // flatness: KNN-independent, fully parallel here (R11-proven)
    float ea = expf(scl[3*p]), eb = expf(scl[3*p+1]), ec = expf(scl[3*p+2]);
    float mn = fminf(ea, fminf(eb, ec));
    float mx = fmaxf(ea, fmaxf(eb, ec));
    float md = fminf(fmaxf(ea, eb), fmaxf(fminf(ea, eb), ec));
    float flat = logf(mx/(mn+1e-8f)+1e-8f) + 0.1f/(fabsf(mx-md)+0.001f);
#pragma unroll
    for (int o = 32; o > 0; o >>= 1) flat += __shfl_down(flat, o, 64);
    if (lane == 0) atomicAdd(flatAcc, flat);
}

// ---------------- build 2: fused scan + scatter (8 blocks x 1024) ----------------
__global__ __launch_bounds__(1024) void gsr_scatter(
    const float* __restrict__ pos, const float* __restrict__ rot,
    const float* __restrict__ opa, unsigned char* __restrict__ ws)
{
    const int* gcnt = (const int*)(ws + WS_GCNT);
    int* cellStart = (int*)(ws + WS_CSTART);
    const int* aux = (const int*)(ws + WS_AUX);
    float4* sPos = (float4*)(ws + WS_SPOS);
    float4* sRot = (float4*)(ws + WS_SROT);
    float* sOpa = (float*)(ws + WS_SOPA);

    __shared__ int sb[NCELL];
    __shared__ int startLds[NCELL];

    const int tid = threadIdx.x;
    int cn = 0;
    if (tid < NCELL) { cn = gcnt[tid]; sb[tid] = cn; }
    __syncthreads();
    for (int off = 1; off < NCELL; off <<= 1) {
        int v = 0;
        if (tid < NCELL && tid >= off) v = sb[tid-off];
        __syncthreads();
        if (tid < NCELL) sb[tid] += v;
        __syncthreads();
    }
    if (tid < NCELL) {
        int incl = sb[tid];
        startLds[tid] = incl - cn;          // exclusive
        if (blockIdx.x == 0) cellStart[tid+1] = incl;   // publish for qcell
    }
    if (blockIdx.x == 0 && tid == 0) cellStart[0] = 0;
    __syncthreads();

    const int p = blockIdx.x*1024 + tid;
    int a = aux[p];
    int c = a & (NCELL-1);
    int dst = startLds[c] + (a >> 9);
    float x = pos[3*p], y = pos[3*p+1], z = pos[3*p+2];
    // identical fmaf shape as query dot product -> self d2 == 0 exactly
    float w = fmaf(x, x, fmaf(y, y, z*z));
    sPos[dst] = make_float4(x, y, z, w);
    sRot[dst] = *(const float4*)(rot + 4*p);
    sOpa[dst] = opa[p];
}

__device__ __forceinline__ void insert5(float (&d)[K5], float v) {
#pragma unroll
    for (int k = 0; k < K5; k++) { float lo = fminf(d[k], v); v = fmaxf(d[k], v); d[k] = lo; }
}
__device__ __forceinline__ void insert9(float (&d)[K9], float v) {
#pragma unroll
    for (int k = 0; k < K9; k++) { float lo = fminf(d[k], v); v = fmaxf(d[k], v); d[k] = lo; }
}

// dual interleaved extract-min over two K5 lists (R10-proven exact)
__device__ __forceinline__ void dual_merge5(const float (&dA)[K5], const float (&dB)[K5],
                                            float& s8A, float& d9A, float& s8B, float& d9B) {
    float a0=dA[0],a1=dA[1],a2=dA[2],a3=dA[3],a4=dA[4];
    float b0=dB[0],b1=dB[1],b2=dB[2],b3=dB[3],b4=dB[4];
    float sA=0.f, sB=0.f, mA=0.f, mB=0.f;
#pragma unroll
    for (int k = 0; k < 9; k++) {
        mA = a0; mB = b0;
#pragma unroll
        for (int o = 32; o > 0; o >>= 1) {
            mA = fminf(mA, __shfl_xor(mA, o, 64));
            mB = fminf(mB, __shfl_xor(mB, o, 64));
        }
        bool tA = (a0 == mA), tB = (b0 == mB);
        a0=tA?a1:a0; a1=tA?a2:a1; a2=tA?a3:a2; a3=tA?a4:a3; a4=tA?1e30f:a4;
        b0=tB?b1:b0; b1=tB?b2:b1; b2=tB?b3:b2; b3=tB?b4:b3; b4=tB?1e30f:b4;
        if (k >= 1) {
            sA += sqrtf(fmaxf(mA, 0.f) + 1e-12f);
            sB += sqrtf(fmaxf(mB, 0.f) + 1e-12f);
        }
    }
    s8A = sA; d9A = mA; s8B = sB; d9B = mB;
}

// serial extract-min over K9 (cold fallback only)
__device__ __forceinline__ void wave_merge9x(const float (&dd)[K9], float& s8, float& d9) {
    float t0=dd[0],t1=dd[1],t2=dd[2],t3=dd[3],t4=dd[4],t5=dd[5],t6=dd[6],t7=dd[7],t8=dd[8];
    float ssum = 0.f, m = 0.f;
#pragma unroll
    for (int k = 0; k < 9; k++) {
        m = t0;
#pragma unroll
        for (int o = 32; o > 0; o >>= 1) m = fminf(m, __shfl_xor(m, o, 64));
        bool take = (t0 == m);
        t0=take?t1:t0; t1=take?t2:t1; t2=take?t3:t2; t3=take?t4:t3;
        t4=take?t5:t4; t5=take?t6:t5; t6=take?t7:t6; t7=take?t8:t7;
        t8=take?1e30f:t8;
        if (k >= 1) ssum += sqrtf(fmaxf(m, 0.f) + 1e-12f);
    }
    s8 = ssum; d9 = m;
}

// ---------------- query: 2 blocks per cell (twins bid, bid+512), LDS-staged box ----------------
__global__ __launch_bounds__(256) void gsr_qcell(
    unsigned char* __restrict__ ws,
    float* __restrict__ out)
{
    const float4* sPos = (const float4*)(ws + WS_SPOS);
    const float4* sRot = (const float4*)(ws + WS_SROT);
    const float* sOpa = (const float*)(ws + WS_SOPA);
    const int* cellStart = (const int*)(ws + WS_CSTART);
    const float* flatAcc = (const float*)(ws + WS_FLAT);
    unsigned int* counter = (unsigned int*)(ws + WS_CNTR);
    float* partials = (float*)(ws + WS_PART);

    __shared__ float4 lp[CAP];
    __shared__ float4 lr[CAP];
    __shared__ float red[4][3];
    __shared__ int lastflag;

    const int tid = threadIdx.x;
    const int lane = tid & 63;
    const int wv = tid >> 6;                 // 0..3
    const int bid = blockIdx.x;
    // twins (bid, bid+512) share a cell; 512 % 8 == 0 -> same XCD under the
    // round-robin bid%8 heuristic (locality hint only, not correctness)
    const int c = bid & (NCELL-1);           // 0..511
    const int half = bid >> 9;               // 0 or 1
    const int gw = half*4 + wv;              // global wave slot 0..7 for this cell
    const int cx = c >> 6, cy = (c >> 3) & 7, cz = c & 7;
    const int zlo = max(cz-1, 0), zhi = min(cz+1, GD-1);
    const int rowStart = cellStart[c], rowEnd = cellStart[c+1];
    const int nrows = rowEnd - rowStart;

    // 9 z-run ranges of the ring-1 box (uniform per block)
    int rsv[9], O[10];
    O[0] = 0;
#pragma unroll
    for (int c9 = 0; c9 < 9; c9++) {
        int jx = cx + c9/3 - 1, jy = cy + c9%3 - 1;
        bool v = (jx >= 0) & (jx < GD) & (jy >= 0) & (jy < GD);
        int b = v ? ((jx*GD + jy)*GD) : 0;
        int lo = cellStart[b + zlo];
        int hi = cellStart[b + zhi + 1];
        rsv[c9] = lo;
        O[c9+1] = O[c9] + (v ? (hi - lo) : 0);
    }
    const int nbox = O[9];
    const bool useLds = (nbox <= CAP);

    if (useLds) {
        for (int t = tid; t < nbox; t += 256) {
            int o = 0;
#pragma unroll
            for (int i = 0; i < 9; i++) {
                bool in = (t >= O[i]) & (t < O[i+1]);
                o = in ? (rsv[i] + (t - O[i])) : o;
            }
            lp[t] = sPos[o];
            lr[t] = sRot[o];
        }
    }
    __syncthreads();

    float asum = 0.f, acnt = 0.f, densAcc = 0.f;

    const int npairs = (nrows + 1) >> 1;
    for (int pi = gw; pi < npairs; pi += 8) {
        const int r0 = rowStart + 2*pi;
        const int r1 = r0 + 1;
        const bool bval = (r1 < rowEnd);
        const float4 P0 = sPos[r0];
        const float4 P1 = bval ? sPos[r1] : P0;
        const float4 Q0 = sRot[r0];
        const float4 Q1 = bval ? sRot[r1] : Q0;

        float dA[K5], dB[K5];
#pragma unroll
        for (int k = 0; k < K5; k++) { dA[k] = 1e30f; dB[k] = 1e30f; }

        for (int g = lane; g < nbox; g += 64) {
            float4 p, rt;
            if (useLds) { p = lp[g]; rt = lr[g]; }
            else {
                int o = 0;
#pragma unroll
                for (int i = 0; i < 9; i++) {
                    bool in = (g >= O[i]) & (g < O[i+1]);
                    o = in ? (rsv[i] + (g - O[i])) : o;
                }
                p = sPos[o]; rt = sRot[o];
            }
            float dt0 = fmaf(P0.x, p.x, fmaf(P0.y, p.y, P0.z*p.z));
            float dt1 = fmaf(P1.x, p.x, fmaf(P1.y, p.y, P1.z*p.z));
            float cA = fmaf(-2.f, dt0, P0.w + p.w);   // d^2; self == 0.0f exactly
            float cB = fmaf(-2.f, dt1, P1.w + p.w);
            insert5(dA, cA);
            insert5(dB, cB);
            bool aA = (cA < ALIGN_T) & (cA != 0.0f);
            bool aB = (cB < ALIGN_T) & (cB != 0.0f) & bval;
            float dq0 = fmaf(Q0.x, rt.x, fmaf(Q0.y, rt.y, fmaf(Q0.z, rt.z, Q0.w*rt.w)));
            float dq1 = fmaf(Q1.x, rt.x, fmaf(Q1.y, rt.y, fmaf(Q1.z, rt.z, Q1.w*rt.w)));
            asum += aA ? (1.f - fabsf(dq0)) : 0.f;
            acnt += aA ? 1.f : 0.f;
            asum += aB ? (1.f - fabsf(dq1)) : 0.f;
            acnt += aB ? 1.f : 0.f;
        }

        float s8A, d9A, s8B, d9B;
        dual_merge5(dA, dB, s8A, d9A, s8B, d9B);

#pragma unroll
        for (int rr = 0; rr < 2; rr++) {
            if (rr == 1 && !bval) break;
            const float Px = rr ? P1.x : P0.x;
            const float Py = rr ? P1.y : P0.y;
            const float Pz = rr ? P1.z : P0.z;
            const float Pw = rr ? P1.w : P0.w;
            float s8 = rr ? s8B : s8A;
            float d9 = rr ? d9B : d9A;
            float cov = 1e30f;
            if (cx-1 > 0)    cov = fminf(cov, Px - (float)(cx-1)*CELL_H);
            if (cx+1 < GD-1) cov = fminf(cov, (float)(cx+2)*CELL_H - Px);
            if (cy-1 > 0)    cov = fminf(cov, Py - (float)(cy-1)*CELL_H);
            if (cy+1 < GD-1) cov = fminf(cov, (float)(cy+2)*CELL_H - Py);
            if (cz-1 > 0)    cov = fminf(cov, Pz - (float)(cz-1)*CELL_H);
            if (cz+1 < GD-1) cov = fminf(cov, (float)(cz+2)*CELL_H - Pz);
            if (!(d9 <= cov*cov)) {
                // cold exact fallback: expanding clipped boxes r>=2 (global, rare)
                float e[K9];
                for (int r = 2; r <= GD; r++) {
#pragma unroll
                    for (int k = 0; k < K9; k++) e[k] = 1e30f;
                    int zl = max(cz-r, 0), zh = min(cz+r, GD-1);
                    for (int jx = max(cx-r,0); jx <= min(cx+r,GD-1); jx++) {
                        for (int jy = max(cy-r,0); jy <= min(cy+r,GD-1); jy++) {
                            int b = (jx*GD+jy)*GD;
                            int rs = cellStart[b+zl], re = cellStart[b+zh+1];
                            for (int o = rs + lane; o < re; o += 64) {
                                float4 p = sPos[o];
                                float dt = fmaf(Px, p.x, fmaf(Py, p.y, Pz*p.z));
                                float cc = fmaf(-2.f, dt, Pw + p.w);
                                insert9(e, cc);
                            }
                        }
                    }
                    wave_merge9x(e, s8, d9);
                    float cv = 1e30f;
                    if (cx-r > 0)    cv = fminf(cv, Px - (float)(cx-r)*CELL_H);
                    if (cx+r < GD-1) cv = fminf(cv, (float)(cx+r+1)*CELL_H - Px);
                    if (cy-r > 0)    cv = fminf(cv, Py - (float)(cy-r)*CELL_H);
                    if (cy+r < GD-1) cv = fminf(cv, (float)(cy+r+1)*CELL_H - Py);
                    if (cz-r > 0)    cv = fminf(cv, Pz - (float)(cz-r)*CELL_H);
                    if (cz+r < GD-1) cv = fminf(cv, (float)(cz+r+1)*CELL_H - Pz);
                    if (d9 <= cv*cv) break;
                }
            }
            if (lane == 0) {
                densAcc += fabsf(s8*0.125f - 0.01f) * sOpa[r0 + rr];
            }
        }
    }

    // block reduction of (asum, acnt, dens)
    float vals[3] = {asum, acnt, densAcc};
#pragma unroll
    for (int qi = 0; qi < 3; qi++) {
        float v = vals[qi];
        for (int o = 32; o > 0; o >>= 1) v += __shfl_down(v, o, 64);
        if (lane == 0) red[wv][qi] = v;
    }
    __syncthreads();
    if (tid == 0) {
        float t0=0,t1=0,t2=0;
        for (int w = 0; w < 4; w++) { t0+=red[w][0]; t1+=red[w][1]; t2+=red[w][2]; }
        *(float4*)(partials + blockIdx.x*4) = make_float4(t0,t1,t2,0.f);
        __threadfence();
        unsigned int old = atomicAdd(counter, 1u);
        lastflag = (old == QBLK-1) ? 1 : 0;
    }
    __syncthreads();
    if (lastflag && wv == 0) {
        __threadfence();
        float t0=0,t1=0,t2=0;
        for (int b = lane; b < QBLK; b += 64) {
            float4 pv = *(const float4*)(partials + b*4);
            t0+=pv.x; t1+=pv.y; t2+=pv.z;
        }
#pragma unroll
        for (int o = 32; o > 0; o >>= 1) {
            t0+=__shfl_down(t0,o,64); t1+=__shfl_down(t1,o,64); t2+=__shfl_down(t2,o,64);
        }
        if (lane == 0) {
            float flat_loss = -(*flatAcc) / (float)NPTS;
            float align_loss = (t1 > 0.f) ? (t0/t1) : 0.f;
            float dens_loss = t2 / (float)NPTS;
            out[0] = 1.0f*flat_loss + 0.5f*align_loss + 0.2f*dens_loss;
        }
    }
}

extern "C" void kernel_launch(void* const* d_in, const int* in_sizes, int n_in,
                              void* d_out, int out_size, void* d_ws, size_t ws_size,
                              hipStream_t stream) {
    const float* pos = (const float*)d_in[0];
    const float* rot = (const float*)d_in[1];
    const float* scl = (const float*)d_in[2];
    const float* opa = (const float*)d_in[3];
    unsigned char* ws = (unsigned char*)d_ws;

    hipMemsetAsync(ws, 0, 2056, stream);    // gcnt + flatAcc + counter
    gsr_count  <<<NPTS/256, 256, 0, stream>>>(pos, scl, ws);
    gsr_scatter<<<NPTS/1024, 1024, 0, stream>>>(pos, rot, opa, ws);
    gsr_qcell  <<<QBLK, 256, 0, stream>>>(ws, (float*)d_out);
}

// Round 14
// 91.196 us; speedup vs baseline: 1.1143x; 1.1143x over previous
//
#include <hip/hip_runtime.h>
#include <math.h>

#define NPTS 8192
#define GD 8
#define NCELL 512                  // GD^3
#define CELL_H (0.3f/(float)GD)    // 0.0375 > 0.02 alignment radius
#define INV_H ((float)GD/0.3f)
#define ALIGN_T 4.0e-4f            // 0.02^2
#define K5 5
#define K9 9
#define CAP 768                    // LDS staging capacity (box ~430)

// ws layout (bytes) — gcnt/flat/cntr contiguous: ONE 2056-B memset clears all
#define WS_GCNT   0                // int[NCELL] (2048 B)
#define WS_FLAT   2048             // float: global flatness sum
#define WS_CNTR   2052             // uint: completion counter
#define WS_PART   2064             // float4[NCELL] partials (8 KB)
#define WS_SPOS   10256            // float4[NPTS] sorted (x,y,z,|p|^2)
#define WS_SROT   141328           // float4[NPTS] sorted rotations
#define WS_SOPA   272400           // float[NPTS] sorted opacity
#define WS_CSTART 305168           // int[NCELL+1]
#define WS_AUX    307224           // int[NPTS] packed (cell | slot<<9)

// ---------------- build 1: count + flatness ----------------
__global__ __launch_bounds__(256) void gsr_count(
    const float* __restrict__ pos, const float* __restrict__ scl,
    unsigned char* __restrict__ ws)
{
    int* gcnt = (int*)(ws + WS_GCNT);
    float* flatAcc = (float*)(ws + WS_FLAT);
    int* aux = (int*)(ws + WS_AUX);

    const int p = blockIdx.x*256 + threadIdx.x;
    const int lane = threadIdx.x & 63;

    float x = pos[3*p], y = pos[3*p+1], z = pos[3*p+2];
    int ix = min((int)(x*INV_H), GD-1);
    int iy = min((int)(y*INV_H), GD-1);
    int iz = min((int)(z*INV_H), GD-1);
    int c = (ix*GD+iy)*GD+iz;
    int slot = atomicAdd(&gcnt[c], 1);
    aux[p] = c | (slot << 9);

    // flatness: KNN-independent, fully parallel here (R11/R13-proven)
    float ea = expf(scl[3*p]), eb = expf(scl[3*p+1]), ec = expf(scl[3*p+2]);
    float mn = fminf(ea, fminf(eb, ec));
    float mx = fmaxf(ea, fmaxf(eb, ec));
    float md = fminf(fmaxf(ea, eb), fmaxf(fminf(ea, eb), ec));
    float flat = logf(mx/(mn+1e-8f)+1e-8f) + 0.1f/(fabsf(mx-md)+0.001f);
#pragma unroll
    for (int o = 32; o > 0; o >>= 1) flat += __shfl_down(flat, o, 64);
    if (lane == 0) atomicAdd(flatAcc, flat);
}

// ---------------- build 2: scan (1 block, R10-proven) ----------------
__global__ __launch_bounds__(NCELL) void gsr_scan(unsigned char* __restrict__ ws)
{
    const int* gcnt = (const int*)(ws + WS_GCNT);
    int* cellStart  = (int*)(ws + WS_CSTART);
    __shared__ int sb[NCELL];
    int t = threadIdx.x;
    int cn = gcnt[t];
    sb[t] = cn;
    __syncthreads();
    for (int off = 1; off < NCELL; off <<= 1) {
        int v = (t >= off) ? sb[t-off] : 0;
        __syncthreads();
        sb[t] += v;
        __syncthreads();
    }
    cellStart[t+1] = sb[t];
    if (t == 0) cellStart[0] = 0;
}

// ---------------- build 3: scatter (R10-proven + sOpa) ----------------
__global__ __launch_bounds__(256) void gsr_scatter(
    const float* __restrict__ pos, const float* __restrict__ rot,
    const float* __restrict__ opa, unsigned char* __restrict__ ws)
{
    float4* sPos = (float4*)(ws + WS_SPOS);
    float4* sRot = (float4*)(ws + WS_SROT);
    float* sOpa = (float*)(ws + WS_SOPA);
    const int* cellStart = (const int*)(ws + WS_CSTART);
    const int* aux = (const int*)(ws + WS_AUX);
    int p = blockIdx.x*256 + threadIdx.x;
    int a = aux[p];
    int c = a & (NCELL-1);
    int dst = cellStart[c] + (a >> 9);
    float x = pos[3*p], y = pos[3*p+1], z = pos[3*p+2];
    // identical fmaf shape as query dot product -> self d2 == 0 exactly
    float w = fmaf(x, x, fmaf(y, y, z*z));
    sPos[dst] = make_float4(x, y, z, w);
    sRot[dst] = *(const float4*)(rot + 4*p);
    sOpa[dst] = opa[p];
}

__device__ __forceinline__ void insert5(float (&d)[K5], float v) {
#pragma unroll
    for (int k = 0; k < K5; k++) { float lo = fminf(d[k], v); v = fmaxf(d[k], v); d[k] = lo; }
}
__device__ __forceinline__ void insert9(float (&d)[K9], float v) {
#pragma unroll
    for (int k = 0; k < K9; k++) { float lo = fminf(d[k], v); v = fmaxf(d[k], v); d[k] = lo; }
}

// dual interleaved extract-min over two K5 lists (R10-proven exact)
__device__ __forceinline__ void dual_merge5(const float (&dA)[K5], const float (&dB)[K5],
                                            float& s8A, float& d9A, float& s8B, float& d9B) {
    float a0=dA[0],a1=dA[1],a2=dA[2],a3=dA[3],a4=dA[4];
    float b0=dB[0],b1=dB[1],b2=dB[2],b3=dB[3],b4=dB[4];
    float sA=0.f, sB=0.f, mA=0.f, mB=0.f;
#pragma unroll
    for (int k = 0; k < 9; k++) {
        mA = a0; mB = b0;
#pragma unroll
        for (int o = 32; o > 0; o >>= 1) {
            mA = fminf(mA, __shfl_xor(mA, o, 64));
            mB = fminf(mB, __shfl_xor(mB, o, 64));
        }
        bool tA = (a0 == mA), tB = (b0 == mB);
        a0=tA?a1:a0; a1=tA?a2:a1; a2=tA?a3:a2; a3=tA?a4:a3; a4=tA?1e30f:a4;
        b0=tB?b1:b0; b1=tB?b2:b1; b2=tB?b3:b2; b3=tB?b4:b3; b4=tB?1e30f:b4;
        if (k >= 1) {
            sA += sqrtf(fmaxf(mA, 0.f) + 1e-12f);
            sB += sqrtf(fmaxf(mB, 0.f) + 1e-12f);
        }
    }
    s8A = sA; d9A = mA; s8B = sB; d9B = mB;
}

// serial extract-min over K9 (cold fallback only)
__device__ __forceinline__ void wave_merge9x(const float (&dd)[K9], float& s8, float& d9) {
    float t0=dd[0],t1=dd[1],t2=dd[2],t3=dd[3],t4=dd[4],t5=dd[5],t6=dd[6],t7=dd[7],t8=dd[8];
    float ssum = 0.f, m = 0.f;
#pragma unroll
    for (int k = 0; k < 9; k++) {
        m = t0;
#pragma unroll
        for (int o = 32; o > 0; o >>= 1) m = fminf(m, __shfl_xor(m, o, 64));
        bool take = (t0 == m);
        t0=take?t1:t0; t1=take?t2:t1; t2=take?t3:t2; t3=take?t4:t3;
        t4=take?t5:t4; t5=take?t6:t5; t6=take?t7:t6; t7=take?t8:t7;
        t8=take?1e30f:t8;
        if (k >= 1) ssum += sqrtf(fmaxf(m, 0.f) + 1e-12f);
    }
    s8 = ssum; d9 = m;
}

// ---------------- query: one block per cell, LDS-staged box (R10-proven) ----------------
__global__ __launch_bounds__(512) void gsr_qcell(
    unsigned char* __restrict__ ws,
    float* __restrict__ out)
{
    const float4* sPos = (const float4*)(ws + WS_SPOS);
    const float4* sRot = (const float4*)(ws + WS_SROT);
    const float* sOpa = (const float*)(ws + WS_SOPA);
    const int* cellStart = (const int*)(ws + WS_CSTART);
    const float* flatAcc = (const float*)(ws + WS_FLAT);
    unsigned int* counter = (unsigned int*)(ws + WS_CNTR);
    float* partials = (float*)(ws + WS_PART);

    __shared__ float4 lp[CAP];
    __shared__ float4 lr[CAP];
    __shared__ float red[8][3];
    __shared__ int lastflag;

    const int tid = threadIdx.x;
    const int lane = tid & 63;
    const int wv = tid >> 6;
    const int c = blockIdx.x;
    const int cx = c >> 6, cy = (c >> 3) & 7, cz = c & 7;
    const int zlo = max(cz-1, 0), zhi = min(cz+1, GD-1);
    const int rowStart = cellStart[c], rowEnd = cellStart[c+1];
    const int nrows = rowEnd - rowStart;

    // 9 z-run ranges of the ring-1 box (uniform per block)
    int rsv[9], O[10];
    O[0] = 0;
#pragma unroll
    for (int c9 = 0; c9 < 9; c9++) {
        int jx = cx + c9/3 - 1, jy = cy + c9%3 - 1;
        bool v = (jx >= 0) & (jx < GD) & (jy >= 0) & (jy < GD);
        int b = v ? ((jx*GD + jy)*GD) : 0;
        int lo = cellStart[b + zlo];
        int hi = cellStart[b + zhi + 1];
        rsv[c9] = lo;
        O[c9+1] = O[c9] + (v ? (hi - lo) : 0);
    }
    const int nbox = O[9];
    const bool useLds = (nbox <= CAP);

    if (useLds) {
        for (int t = tid; t < nbox; t += 512) {
            int o = 0;
#pragma unroll
            for (int i = 0; i < 9; i++) {
                bool in = (t >= O[i]) & (t < O[i+1]);
                o = in ? (rsv[i] + (t - O[i])) : o;
            }
            lp[t] = sPos[o];
            lr[t] = sRot[o];
        }
    }
    __syncthreads();

    float asum = 0.f, acnt = 0.f, densAcc = 0.f;

    const int npairs = (nrows + 1) >> 1;
    for (int pi = wv; pi < npairs; pi += 8) {
        const int r0 = rowStart + 2*pi;
        const int r1 = r0 + 1;
        const bool bval = (r1 < rowEnd);
        const float4 P0 = sPos[r0];
        const float4 P1 = bval ? sPos[r1] : P0;
        const float4 Q0 = sRot[r0];
        const float4 Q1 = bval ? sRot[r1] : Q0;

        float dA[K5], dB[K5];
#pragma unroll
        for (int k = 0; k < K5; k++) { dA[k] = 1e30f; dB[k] = 1e30f; }

        for (int g = lane; g < nbox; g += 64) {
            float4 p, rt;
            if (useLds) { p = lp[g]; rt = lr[g]; }
            else {
                int o = 0;
#pragma unroll
                for (int i = 0; i < 9; i++) {
                    bool in = (g >= O[i]) & (g < O[i+1]);
                    o = in ? (rsv[i] + (g - O[i])) : o;
                }
                p = sPos[o]; rt = sRot[o];
            }
            float dt0 = fmaf(P0.x, p.x, fmaf(P0.y, p.y, P0.z*p.z));
            float dt1 = fmaf(P1.x, p.x, fmaf(P1.y, p.y, P1.z*p.z));
            float cA = fmaf(-2.f, dt0, P0.w + p.w);   // d^2; self == 0.0f exactly
            float cB = fmaf(-2.f, dt1, P1.w + p.w);
            insert5(dA, cA);
            insert5(dB, cB);
            bool aA = (cA < ALIGN_T) & (cA != 0.0f);
            bool aB = (cB < ALIGN_T) & (cB != 0.0f) & bval;
            float dq0 = fmaf(Q0.x, rt.x, fmaf(Q0.y, rt.y, fmaf(Q0.z, rt.z, Q0.w*rt.w)));
            float dq1 = fmaf(Q1.x, rt.x, fmaf(Q1.y, rt.y, fmaf(Q1.z, rt.z, Q1.w*rt.w)));
            asum += aA ? (1.f - fabsf(dq0)) : 0.f;
            acnt += aA ? 1.f : 0.f;
            asum += aB ? (1.f - fabsf(dq1)) : 0.f;
            acnt += aB ? 1.f : 0.f;
        }

        float s8A, d9A, s8B, d9B;
        dual_merge5(dA, dB, s8A, d9A, s8B, d9B);

#pragma unroll
        for (int rr = 0; rr < 2; rr++) {
            if (rr == 1 && !bval) break;
            const float Px = rr ? P1.x : P0.x;
            const float Py = rr ? P1.y : P0.y;
            const float Pz = rr ? P1.z : P0.z;
            const float Pw = rr ? P1.w : P0.w;
            float s8 = rr ? s8B : s8A;
            float d9 = rr ? d9B : d9A;
            float cov = 1e30f;
            if (cx-1 > 0)    cov = fminf(cov, Px - (float)(cx-1)*CELL_H);
            if (cx+1 < GD-1) cov = fminf(cov, (float)(cx+2)*CELL_H - Px);
            if (cy-1 > 0)    cov = fminf(cov, Py - (float)(cy-1)*CELL_H);
            if (cy+1 < GD-1) cov = fminf(cov, (float)(cy+2)*CELL_H - Py);
            if (cz-1 > 0)    cov = fminf(cov, Pz - (float)(cz-1)*CELL_H);
            if (cz+1 < GD-1) cov = fminf(cov, (float)(cz+2)*CELL_H - Pz);
            if (!(d9 <= cov*cov)) {
                // cold exact fallback: expanding clipped boxes r>=2 (global, rare)
                float e[K9];
                for (int r = 2; r <= GD; r++) {
#pragma unroll
                    for (int k = 0; k < K9; k++) e[k] = 1e30f;
                    int zl = max(cz-r, 0), zh = min(cz+r, GD-1);
                    for (int jx = max(cx-r,0); jx <= min(cx+r,GD-1); jx++) {
                        for (int jy = max(cy-r,0); jy <= min(cy+r,GD-1); jy++) {
                            int b = (jx*GD+jy)*GD;
                            int rs = cellStart[b+zl], re = cellStart[b+zh+1];
                            for (int o = rs + lane; o < re; o += 64) {
                                float4 p = sPos[o];
                                float dt = fmaf(Px, p.x, fmaf(Py, p.y, Pz*p.z));
                                float cc = fmaf(-2.f, dt, Pw + p.w);
                                insert9(e, cc);
                            }
                        }
                    }
                    wave_merge9x(e, s8, d9);
                    float cv = 1e30f;
                    if (cx-r > 0)    cv = fminf(cv, Px - (float)(cx-r)*CELL_H);
                    if (cx+r < GD-1) cv = fminf(cv, (float)(cx+r+1)*CELL_H - Px);
                    if (cy-r > 0)    cv = fminf(cv, Py - (float)(cy-r)*CELL_H);
                    if (cy+r < GD-1) cv = fminf(cv, (float)(cy+r+1)*CELL_H - Py);
                    if (cz-r > 0)    cv = fminf(cv, Pz - (float)(cz-r)*CELL_H);
                    if (cz+r < GD-1) cv = fminf(cv, (float)(cz+r+1)*CELL_H - Pz);
                    if (d9 <= cv*cv) break;
                }
            }
            if (lane == 0) {
                densAcc += fabsf(s8*0.125f - 0.01f) * sOpa[r0 + rr];
            }
        }
    }

    // block reduction of (asum, acnt, dens)
    float vals[3] = {asum, acnt, densAcc};
#pragma unroll
    for (int qi = 0; qi < 3; qi++) {
        float v = vals[qi];
        for (int o = 32; o > 0; o >>= 1) v += __shfl_down(v, o, 64);
        if (lane == 0) red[wv][qi] = v;
    }
    __syncthreads();
    if (tid == 0) {
        float t0=0,t1=0,t2=0;
        for (int w = 0; w < 8; w++) { t0+=red[w][0]; t1+=red[w][1]; t2+=red[w][2]; }
        *(float4*)(partials + blockIdx.x*4) = make_float4(t0,t1,t2,0.f);
        __threadfence();
        unsigned int old = atomicAdd(counter, 1u);
        lastflag = (old == NCELL-1) ? 1 : 0;
    }
    __syncthreads();
    if (lastflag && wv == 0) {
        __threadfence();
        float t0=0,t1=0,t2=0;
        for (int b = lane; b < NCELL; b += 64) {
            float4 pv = *(const float4*)(partials + b*4);
            t0+=pv.x; t1+=pv.y; t2+=pv.z;
        }
#pragma unroll
        for (int o = 32; o > 0; o >>= 1) {
            t0+=__shfl_down(t0,o,64); t1+=__shfl_down(t1,o,64); t2+=__shfl_down(t2,o,64);
        }
        if (lane == 0) {
            float flat_loss = -(*flatAcc) / (float)NPTS;
            float align_loss = (t1 > 0.f) ? (t0/t1) : 0.f;
            float dens_loss = t2 / (float)NPTS;
            out[0] = 1.0f*flat_loss + 0.5f*align_loss + 0.2f*dens_loss;
        }
    }
}

extern "C" void kernel_launch(void* const* d_in, const int* in_sizes, int n_in,
                              void* d_out, int out_size, void* d_ws, size_t ws_size,
                              hipStream_t stream) {
    const float* pos = (const float*)d_in[0];
    const float* rot = (const float*)d_in[1];
    const float* scl = (const float*)d_in[2];
    const float* opa = (const float*)d_in[3];
    unsigned char* ws = (unsigned char*)d_ws;

    hipMemsetAsync(ws, 0, 2056, stream);    // gcnt + flatAcc + counter
    gsr_count  <<<NPTS/256, 256, 0, stream>>>(pos, scl, ws);
    gsr_scan   <<<1, NCELL, 0, stream>>>(ws);
    gsr_scatter<<<NPTS/256, 256, 0, stream>>>(pos, rot, opa, ws);
    gsr_qcell  <<<NCELL, 512, 0, stream>>>(ws, (float*)d_out);
}